// Round 19
// baseline (114.626 us; speedup 1.0000x reference)
//
#include <hip/hip_runtime.h>
#include <hip/hip_bf16.h>
#include <stdint.h>

#define DIM   1024
#define NH    16
#define HDIM  64
#define SEQ   2048
#define BATCH 2
#define BHN   32            // BATCH*NH
#define MTOK  4096          // BATCH*SEQ
#define SC2   0.18033688f   // (1/sqrt(64)) * log2(e)

using u16 = unsigned short;
using u32 = unsigned int;
typedef __attribute__((ext_vector_type(8))) short short8;   // MFMA A/B frag (8 bf16)
typedef __attribute__((ext_vector_type(4))) float f32x4;    // 16x16 MFMA C/D frag
typedef __attribute__((ext_vector_type(16))) float f32x16;  // 32x32 MFMA C/D frag

__device__ __forceinline__ u16 f2bf(float f) {
  __hip_bfloat16 h = __float2bfloat16(f);
  return *reinterpret_cast<u16*>(&h);
}
__device__ __forceinline__ u32 pk2(float lo, float hi) {
  return (u32)f2bf(lo) | ((u32)f2bf(hi) << 16);
}
// hardware packed f32->bf16 (RNE), 1 instr for 2 values
__device__ __forceinline__ u32 cvtpk(float lo, float hi) {
  u32 r;
  asm("v_cvt_pk_bf16_f32 %0, %1, %2" : "=v"(r) : "v"(lo), "v"(hi));
  return r;
}
// raw 2^x, no libm range fixup (inputs bounded by construction)
__device__ __forceinline__ float vexp2(float x) {
  float r;
  asm("v_exp_f32 %0, %1" : "=v"(r) : "v"(x));
  return r;
}

// async global->LDS, 16B per lane
__device__ __forceinline__ void gload16(const void* g, void* lds) {
  __builtin_amdgcn_global_load_lds(
      (const __attribute__((address_space(1))) u32*)g,
      (__attribute__((address_space(3))) u32*)lds, 16, 0, 0);
}

// ---------------- fused prep: fp32->bf16 x3 + RoPE cos/sin table ----------------
#define PREP_A 1048576              // x: MTOK*DIM/4
#define PREP_B 1835008              // + qkv_w: 3*DIM*DIM/4
#define PREP_C 2097152              // + proj_w: DIM*DIM/4
#define PREP_E 2162688              // + tab: SEQ*32
__global__ void k_prep(const float4* __restrict__ x, const float4* __restrict__ qw,
                       const float4* __restrict__ pw, ushort4* __restrict__ xb,
                       ushort4* __restrict__ qwb, ushort4* __restrict__ pwb,
                       float2* __restrict__ tab) {
  int i = blockIdx.x * blockDim.x + threadIdx.x;
  if (i < PREP_A) {
    float4 v = x[i];
    xb[i] = make_ushort4(f2bf(v.x), f2bf(v.y), f2bf(v.z), f2bf(v.w));
  } else if (i < PREP_B) {
    int j = i - PREP_A;
    float4 v = qw[j];
    qwb[j] = make_ushort4(f2bf(v.x), f2bf(v.y), f2bf(v.z), f2bf(v.w));
  } else if (i < PREP_C) {
    int j = i - PREP_B;
    float4 v = pw[j];
    pwb[j] = make_ushort4(f2bf(v.x), f2bf(v.y), f2bf(v.z), f2bf(v.w));
  } else if (i < PREP_E) {
    int j = i - PREP_C;
    int n = j >> 5, f = j & 31;
    float inv = powf(10000.f, -(2.f * f) / 64.f);
    float s, c;
    sincosf((float)n * inv, &s, &c);
    tab[j] = make_float2(c, s);
  }
}

// ---------------- bf16 GEMM: C = A * Bt^T, 128x128 tile, BK=64 ----------------
// R16-proven loop (single-buffer LDS + __syncthreads; compiler-scheduled).
// 1-D grid with XCD-locality decode: xcd=bid&7 owns 4 row-panels (A stays hot in
// its L2); within XCD row-in-group fastest -> B panel reused 4x back-to-back.
// Epilogue: 4x4 in-quad register transpose -> wide stores:
//   EPI=0: float4 fp32 out + bias (proj)
//   EPI=1: bias + in-lane RoPE + uint2 scatter; q pre-scaled by SC2;
//     K tiled [bh][n/64][d/8][n&63][d&7]; V tiled [bh][n/64][(n&63)/8][d][n&7]
template <int EPI>
__global__ __launch_bounds__(256, 2) void k_gemm(
    const u16* __restrict__ A, const u16* __restrict__ Bt,
    const float* __restrict__ bias, int K,
    float* __restrict__ out_f, u16* __restrict__ qb, u16* __restrict__ kb,
    u16* __restrict__ vtb, const float2* __restrict__ tab) {
  __shared__ u16 As[128 * 64];
  __shared__ u16 Bs[128 * 64];
  const int tid = threadIdx.x;
  const int wid = tid >> 6, lane = tid & 63;
  const int lq = lane & 15, g = lane >> 4;
  const int wr = wid >> 1, wc = wid & 1;
  // XCD-locality decode: 4 row-panels per XCD, row-in-group fastest
  const int bid = blockIdx.x;
  const int xcd = bid & 7, idx = bid >> 3;
  const int brow = (xcd * 4 + (idx & 3)) * 128;
  const int bcol = (idx >> 2) * 128;
  f32x4 acc[4][4] = {};
  const u16* Ab = A + (size_t)brow * K;
  const u16* Bb = Bt + (size_t)bcol * K;

  for (int k0 = 0; k0 < K; k0 += 64) {
#pragma unroll
    for (int t = 0; t < 4; t++) {
      int rl = wid * 32 + t * 8 + (lane >> 3);
      int cs = (lane & 7) ^ (rl & 7);
      gload16(Ab + (size_t)rl * K + k0 + cs * 8, &As[(wid * 32 + t * 8) * 64]);
      gload16(Bb + (size_t)rl * K + k0 + cs * 8, &Bs[(wid * 32 + t * 8) * 64]);
    }
    __syncthreads();
#pragma unroll
    for (int kc = 0; kc < 2; kc++) {
      short8 af[4], bfr[4];
#pragma unroll
      for (int mt = 0; mt < 4; mt++) {
        int r = wr * 64 + mt * 16 + lq;
        af[mt] = *reinterpret_cast<const short8*>(&As[r * 64 + (((kc * 4 + g) ^ (r & 7)) * 8)]);
      }
#pragma unroll
      for (int nt = 0; nt < 4; nt++) {
        int r = wc * 64 + nt * 16 + lq;
        bfr[nt] = *reinterpret_cast<const short8*>(&Bs[r * 64 + (((kc * 4 + g) ^ (r & 7)) * 8)]);
      }
#pragma unroll
      for (int mt = 0; mt < 4; mt++)
#pragma unroll
        for (int nt = 0; nt < 4; nt++)
          acc[mt][nt] = __builtin_amdgcn_mfma_f32_16x16x32_bf16(af[mt], bfr[nt], acc[mt][nt], 0, 0, 0);
    }
    __syncthreads();
  }

#pragma unroll
  for (int mt = 0; mt < 4; mt++) {
    int row0 = brow + wr * 64 + mt * 16 + g * 4;
#pragma unroll
    for (int nt = 0; nt < 4; nt++) {
      int col = bcol + wc * 64 + nt * 16 + lq;
      float bv = bias[col];
      float v0 = acc[mt][nt][0] + bv;
      float v1 = acc[mt][nt][1] + bv;
      float v2 = acc[mt][nt][2] + bv;
      float v3 = acc[mt][nt][3] + bv;

      if (EPI == 1) {
        int which = col >> 10;
        if (which == 2) {
          // V tiled store: 4 consecutive n within one (kvchunk,d) run -> one 8B store
          int hd = col & 1023, d = hd & 63;
          int bb = row0 >> 11, n0 = row0 & 2047;
          int bh = bb * NH + (hd >> 6);
          uint2 pv = make_uint2(pk2(v0, v1), pk2(v2, v3));
          size_t idx2 = ((((size_t)bh * 32 + (n0 >> 6)) * 8 + ((n0 >> 3) & 7)) * 64 + d) * 8 + (n0 & 7);
          *reinterpret_cast<uint2*>(&vtb[idx2]) = pv;
          continue;
        }
      }

      // ---- 4x4 in-quad transpose: lane -> token row0+(lane&3), features f0..f0+3 ----
      { float u = (lane & 1) ? v0 : v1; float s = __shfl_xor(u, 1); if (lane & 1) v0 = s; else v1 = s; }
      { float u = (lane & 1) ? v2 : v3; float s = __shfl_xor(u, 1); if (lane & 1) v2 = s; else v3 = s; }
      { float u = (lane & 2) ? v0 : v2; float s = __shfl_xor(u, 2); if (lane & 2) v0 = s; else v2 = s; }
      { float u = (lane & 2) ? v1 : v3; float s = __shfl_xor(u, 2); if (lane & 2) v1 = s; else v3 = s; }
      const int rr = row0 + (lane & 3);          // token
      const int f0 = col & ~3;                   // feature base (4-aligned)

      if (EPI == 0) {
        *reinterpret_cast<float4*>(&out_f[(size_t)rr * DIM + f0]) = make_float4(v0, v1, v2, v3);
      } else {
        int which = f0 >> 10, hd = f0 & 1023, hdh = hd >> 6, d0 = hd & 63;
        int bb = rr >> 11, n = rr & 2047;
        int bh = bb * NH + hdh;
        // in-lane RoPE: (v0,v1) and (v2,v3) are even/odd pairs
        float2 cs0 = tab[n * 32 + (d0 >> 1)];
        float2 cs1 = tab[n * 32 + (d0 >> 1) + 1];
        float e0 = fmaf(-v1, cs0.y, v0 * cs0.x);
        float o0 = fmaf( v0, cs0.y, v1 * cs0.x);
        float e1 = fmaf(-v3, cs1.y, v2 * cs1.x);
        float o1 = fmaf( v2, cs1.y, v3 * cs1.x);
        if (which == 0) {
          uint2 pv = make_uint2(pk2(e0 * SC2, o0 * SC2), pk2(e1 * SC2, o1 * SC2));
          *reinterpret_cast<uint2*>(&qb[((size_t)bh * SEQ + n) * HDIM + d0]) = pv;
        } else {
          size_t idx2 = ((((size_t)bh * 32 + (n >> 6)) * 8 + (d0 >> 3)) * 64 + (n & 63)) * 8 + (d0 & 7);
          *reinterpret_cast<uint2*>(&kb[idx2]) = make_uint2(pk2(e0, o0), pk2(e1, o1));
        }
      }
    }
  }
}

// ---------------- flash attention: K in LDS, V register-direct (pipe balance) ----------------
// grid 512 (XCD-swizzled: 4 heads/XCD), 256 thr = 4 waves x 32 q.
// K staged once per block into 4 rotating 8KB LDS buffers (2 gloads/wave/tile);
// V read register-direct per wave (8 coalesced dwordx4/tile, double-buffered regs).
// Halves LDS-pipe traffic vs R15 while keeping TA traffic well under the R14 wall.
// vmcnt invariant: per body issue {V(t) x8, K-stage(t+2) x2}; vmcnt(2) at top of
// body(t) -> K(t) staged AND V(t-1) landed; only K(t+1)'s 2 loads stay in flight.
// QK(t) overlaps exp/pack(t-1)+PV(t-1). No-max softmax, raw v_exp, ones-MFMA denom.
__global__ __launch_bounds__(256) void k_attn(
    const u16* __restrict__ qg, const u16* __restrict__ kg,
    const u16* __restrict__ vg, u16* __restrict__ aout) {
  __shared__ __align__(16) char smem[32768];   // 4 x 8KB K buffers
  const int tid = threadIdx.x;
  const int wid = tid >> 6, lane = tid & 63;
  const int l31 = lane & 31, h = lane >> 5;

  // XCD-aware decode: bid&7 = XCD; 4 consecutive heads per XCD
  const int bid = blockIdx.x;
  const int xcd = bid & 7, slot = bid >> 3;      // slot 0..63
  const int bh = xcd * 4 + (slot >> 4);
  const int qt = slot & 15;
  const int b = bh >> 4, hh = bh & 15;
  const int q0 = qt * 128 + wid * 32;            // this wave's 32 q-rows

  const u16* kbase = kg + (size_t)bh * SEQ * HDIM;   // 32 tiles x 4096 u16 (blocked)
  const u16* vb0   = vg + (size_t)bh * SEQ * HDIM + h * 512 + l31 * 8;  // per-lane V base

  // Q B-frags (pre-scaled by SC2): chunk c -> d = c*16 + h*8 + j
  const u16* qrow = qg + ((size_t)bh * SEQ + q0 + l31) * HDIM;
  short8 qf[4];
#pragma unroll
  for (int c = 0; c < 4; c++)
    qf[c] = *reinterpret_cast<const short8*>(qrow + c * 16 + h * 8);

  // all-ones bf16 A-frag for the denominator MFMA (layout-independent)
  short8 ones;
#pragma unroll
  for (int i = 0; i < 8; i++) ones[i] = (short)0x3F80;

  // chunk-major K frag offsets: block (2c+h), row l31 (+512B for rows 32..63)
  int koff[4];
#pragma unroll
  for (int c = 0; c < 4; c++)
    koff[c] = (2 * c + h) * 1024 + l31 * 16;

  f32x16 sA0, sA1, sB0, sB1;
  f32x16 oA = {}, oB = {}, ls = {};
  short8 vfA[8], vfB[8];

  // stage one 64-kv K tile (8KB): wave stages chunk-blocks {wid, wid+4}; 2 gloads
  auto stageK = [&](int buf, int tidx) {
    char* kd = smem + buf * 8192;
    const u16* kt = kbase + (size_t)tidx * 4096 + lane * 8;
    gload16(kt + wid * 512,       kd + wid * 1024);
    gload16(kt + (wid + 4) * 512, kd + (wid + 4) * 1024);
  };

  const int NT = SEQ / 64;                       // 32

  // one pipelined tile: vmcnt(2)+barrier; issue V(t)->vn; QK(t)->sn from LDS;
  // stage K(t+2); exp/pack(S(t-1)=sc) + PV(t-1) with vc.
  auto body = [&](f32x16& sc0, f32x16& sc1, f32x16& sn0, f32x16& sn1,
                  short8 (&vc)[8], short8 (&vn)[8], int t, bool last) {
    if (!last) asm volatile("s_waitcnt vmcnt(2)" ::: "memory");
    else       asm volatile("s_waitcnt vmcnt(0)" ::: "memory");
    __builtin_amdgcn_s_barrier();                // K buf(t) staged for everyone

    const char* kbp = smem + (t & 3) * 8192;

    // issue V(t) register loads (consumed next body; full body of flight time)
    {
      const u16* vn_p = vb0 + (size_t)t * 4096;
#pragma unroll
      for (int c = 0; c < 4; c++) {
        vn[2 * c]     = *reinterpret_cast<const short8*>(vn_p + c * 1024);
        vn[2 * c + 1] = *reinterpret_cast<const short8*>(vn_p + c * 1024 + 256);
      }
    }

#pragma unroll
    for (int c = 0; c < 4; c++) {
      short8 kf0 = *reinterpret_cast<const short8*>(kbp + koff[c]);
      short8 kf1 = *reinterpret_cast<const short8*>(kbp + koff[c] + 512);
      __builtin_amdgcn_s_setprio(1);
      if (c == 0) {
        f32x16 z = {};
        sn0 = __builtin_amdgcn_mfma_f32_32x32x16_bf16(kf0, qf[0], z, 0, 0, 0);
        sn1 = __builtin_amdgcn_mfma_f32_32x32x16_bf16(kf1, qf[0], z, 0, 0, 0);
      } else {
        sn0 = __builtin_amdgcn_mfma_f32_32x32x16_bf16(kf0, qf[c], sn0, 0, 0, 0);
        sn1 = __builtin_amdgcn_mfma_f32_32x32x16_bf16(kf1, qf[c], sn1, 0, 0, 0);
      }
      __builtin_amdgcn_s_setprio(0);

      if (c == 0 && t + 2 < NT) stageK((t + 2) & 3, t + 2);  // 2 gloads, newest

      // exp + pack chunk c of S(t-1)
      f32x16& sv = (c < 2) ? sc0 : sc1;
      const int e0 = (c & 1) * 8;
      float e[8];
#pragma unroll
      for (int j = 0; j < 8; j++) e[j] = vexp2(sv[e0 + j]);
      u32 a0 = cvtpk(e[0], e[1]), a1 = cvtpk(e[2], e[3]);
      u32 b0 = cvtpk(e[4], e[5]), b1 = cvtpk(e[6], e[7]);
      auto r0 = __builtin_amdgcn_permlane32_swap(a0, b0, false, false);
      auto r1 = __builtin_amdgcn_permlane32_swap(a1, b1, false, false);
      union { u32 u[4]; short8 v; } pp;
      pp.u[0] = r0[0]; pp.u[1] = r1[0]; pp.u[2] = r0[1]; pp.u[3] = r1[1];
      short8 pf = pp.v;

      __builtin_amdgcn_s_setprio(1);
      oA = __builtin_amdgcn_mfma_f32_32x32x16_bf16(vc[2 * c],     pf, oA, 0, 0, 0);
      oB = __builtin_amdgcn_mfma_f32_32x32x16_bf16(vc[2 * c + 1], pf, oB, 0, 0, 0);
      ls = __builtin_amdgcn_mfma_f32_32x32x16_bf16(ones,          pf, ls, 0, 0, 0);
      __builtin_amdgcn_s_setprio(0);
    }
  };

  // ---- prologue: stage K(0),K(1); V(0)->vfA; QK(0)->sA; stage K(2) ----
  stageK(0, 0);
  stageK(1, 1);
  asm volatile("s_waitcnt vmcnt(2)" ::: "memory");
  __builtin_amdgcn_s_barrier();
  {
#pragma unroll
    for (int c = 0; c < 4; c++) {
      vfA[2 * c]     = *reinterpret_cast<const short8*>(vb0 + c * 1024);
      vfA[2 * c + 1] = *reinterpret_cast<const short8*>(vb0 + c * 1024 + 256);
    }
    const char* kbp = smem;                      // buf0 = tile 0
    f32x16 z = {};
    sA0 = z; sA1 = z;
#pragma unroll
    for (int c = 0; c < 4; c++) {
      short8 kf0 = *reinterpret_cast<const short8*>(kbp + koff[c]);
      short8 kf1 = *reinterpret_cast<const short8*>(kbp + koff[c] + 512);
      __builtin_amdgcn_s_setprio(1);
      sA0 = __builtin_amdgcn_mfma_f32_32x32x16_bf16(kf0, qf[c], sA0, 0, 0, 0);
      sA1 = __builtin_amdgcn_mfma_f32_32x32x16_bf16(kf1, qf[c], sA1, 0, 0, 0);
      __builtin_amdgcn_s_setprio(0);
      if (c == 0) stageK(2, 2);
    }
  }

  // ---- main: t = 1..30 in pairs, then t = 31 ----
#pragma unroll 1
  for (int i = 0; i < 15; i++) {
    body(sA0, sA1, sB0, sB1, vfA, vfB, 2 * i + 1, false);  // consume S(2i)/V(2i)
    body(sB0, sB1, sA0, sA1, vfB, vfA, 2 * i + 2, false);  // consume S(2i+1)/V(2i+1)
  }
  body(sA0, sA1, sB0, sB1, vfA, vfB, 31, true);            // consume S(30)/V(30)

  // ---- epilogue: consume S(31)=sB with V(31)=vfB (register-resident) ----
#pragma unroll
  for (int c = 0; c < 4; c++) {
    f32x16& sv = (c < 2) ? sB0 : sB1;
    const int e0 = (c & 1) * 8;
    float e[8];
#pragma unroll
    for (int j = 0; j < 8; j++) e[j] = vexp2(sv[e0 + j]);
    u32 a0 = cvtpk(e[0], e[1]), a1 = cvtpk(e[2], e[3]);
    u32 b0 = cvtpk(e[4], e[5]), b1 = cvtpk(e[6], e[7]);
    auto r0 = __builtin_amdgcn_permlane32_swap(a0, b0, false, false);
    auto r1 = __builtin_amdgcn_permlane32_swap(a1, b1, false, false);
    union { u32 u[4]; short8 v; } pp;
    pp.u[0] = r0[0]; pp.u[1] = r1[0]; pp.u[2] = r0[1]; pp.u[3] = r1[1];
    short8 pf = pp.v;
    oA = __builtin_amdgcn_mfma_f32_32x32x16_bf16(vfB[2 * c],     pf, oA, 0, 0, 0);
    oB = __builtin_amdgcn_mfma_f32_32x32x16_bf16(vfB[2 * c + 1], pf, oB, 0, 0, 0);
    ls = __builtin_amdgcn_mfma_f32_32x32x16_bf16(ones,           pf, ls, 0, 0, 0);
  }

  // ls[r] identical for all r: full-sequence row sum for q = l31 (both lane halves)
  float invl = 1.0f / ls[0];
  int n = q0 + l31;
  u16* op = aout + ((size_t)(b * SEQ + n)) * DIM + hh * HDIM;
#pragma unroll
  for (int g = 0; g < 4; g++) {
    u32 w0 = pk2(oA[4 * g] * invl, oA[4 * g + 1] * invl);
    u32 w1 = pk2(oA[4 * g + 2] * invl, oA[4 * g + 3] * invl);
    *reinterpret_cast<uint2*>(op + 8 * g + 4 * h) = make_uint2(w0, w1);
    u32 x0 = pk2(oB[4 * g] * invl, oB[4 * g + 1] * invl);
    u32 x1 = pk2(oB[4 * g + 2] * invl, oB[4 * g + 3] * invl);
    *reinterpret_cast<uint2*>(op + 32 + 8 * g + 4 * h) = make_uint2(x0, x1);
  }
}

// ---------------- launch ----------------
extern "C" void kernel_launch(void* const* d_in, const int* in_sizes, int n_in,
                              void* d_out, int out_size, void* d_ws, size_t ws_size,
                              hipStream_t stream) {
  (void)in_sizes; (void)n_in; (void)out_size; (void)ws_size;
  const float* x      = (const float*)d_in[0];
  const float* qkv_w  = (const float*)d_in[1];
  const float* qkv_b  = (const float*)d_in[2];
  const float* proj_w = (const float*)d_in[3];
  const float* proj_b = (const float*)d_in[4];
  float* out = (float*)d_out;

  char* w = (char*)d_ws;
  u16* xb     = (u16*)w;  w += (size_t)MTOK * DIM * 2;
  u16* wqkvb  = (u16*)w;  w += (size_t)3 * DIM * DIM * 2;
  u16* wprojb = (u16*)w;  w += (size_t)DIM * DIM * 2;
  u16* qb     = (u16*)w;  w += (size_t)BHN * SEQ * HDIM * 2;
  u16* kb     = (u16*)w;  w += (size_t)BHN * SEQ * HDIM * 2;
  u16* vtb    = (u16*)w;  w += (size_t)BHN * SEQ * HDIM * 2;
  u16* aout   = (u16*)w;  w += (size_t)MTOK * DIM * 2;
  float2* tab = (float2*)w;

  k_prep<<<(PREP_E + 255) / 256, 256, 0, stream>>>(
      (const float4*)x, (const float4*)qkv_w, (const float4*)proj_w,
      (ushort4*)xb, (ushort4*)wqkvb, (ushort4*)wprojb, tab);

  // grid: 24 cols x 32 rows = 768 blocks, XCD-locality decode inside
  k_gemm<1><<<768, 256, 0, stream>>>(
      xb, wqkvb, qkv_b, DIM, nullptr, qb, kb, vtb, tab);

  k_attn<<<512, 256, 0, stream>>>(qb, kb, vtb, aout);

  // grid: 8 cols x 32 rows = 256 blocks
  k_gemm<0><<<256, 256, 0, stream>>>(
      aout, wprojb, proj_b, DIM, out, nullptr, nullptr, nullptr, nullptr);
}

// Round 20
// 111.743 us; speedup vs baseline: 1.0258x; 1.0258x over previous
//
#include <hip/hip_runtime.h>
#include <hip/hip_bf16.h>
#include <stdint.h>

#define DIM   1024
#define NH    16
#define HDIM  64
#define SEQ   2048
#define BATCH 2
#define BHN   32            // BATCH*NH
#define MTOK  4096          // BATCH*SEQ
#define SC2   0.18033688f   // (1/sqrt(64)) * log2(e)

using u16 = unsigned short;
using u32 = unsigned int;
typedef __attribute__((ext_vector_type(8))) short short8;   // MFMA A/B frag (8 bf16)
typedef __attribute__((ext_vector_type(4))) float f32x4;    // 16x16 MFMA C/D frag
typedef __attribute__((ext_vector_type(16))) float f32x16;  // 32x32 MFMA C/D frag

__device__ __forceinline__ u16 f2bf(float f) {
  __hip_bfloat16 h = __float2bfloat16(f);
  return *reinterpret_cast<u16*>(&h);
}
__device__ __forceinline__ u32 pk2(float lo, float hi) {
  return (u32)f2bf(lo) | ((u32)f2bf(hi) << 16);
}
// hardware packed f32->bf16 (RNE), 1 instr for 2 values
__device__ __forceinline__ u32 cvtpk(float lo, float hi) {
  u32 r;
  asm("v_cvt_pk_bf16_f32 %0, %1, %2" : "=v"(r) : "v"(lo), "v"(hi));
  return r;
}
// raw 2^x, no libm range fixup (inputs bounded by construction)
__device__ __forceinline__ float vexp2(float x) {
  float r;
  asm("v_exp_f32 %0, %1" : "=v"(r) : "v"(x));
  return r;
}

// async global->LDS, 16B per lane
__device__ __forceinline__ void gload16(const void* g, void* lds) {
  __builtin_amdgcn_global_load_lds(
      (const __attribute__((address_space(1))) u32*)g,
      (__attribute__((address_space(3))) u32*)lds, 16, 0, 0);
}

// ---------------- fused prep: fp32->bf16 x3 + RoPE cos/sin table ----------------
#define PREP_A 1048576              // x: MTOK*DIM/4
#define PREP_B 1835008              // + qkv_w: 3*DIM*DIM/4
#define PREP_C 2097152              // + proj_w: DIM*DIM/4
#define PREP_E 2162688              // + tab: SEQ*32
__global__ void k_prep(const float4* __restrict__ x, const float4* __restrict__ qw,
                       const float4* __restrict__ pw, ushort4* __restrict__ xb,
                       ushort4* __restrict__ qwb, ushort4* __restrict__ pwb,
                       float2* __restrict__ tab) {
  int i = blockIdx.x * blockDim.x + threadIdx.x;
  if (i < PREP_A) {
    float4 v = x[i];
    xb[i] = make_ushort4(f2bf(v.x), f2bf(v.y), f2bf(v.z), f2bf(v.w));
  } else if (i < PREP_B) {
    int j = i - PREP_A;
    float4 v = qw[j];
    qwb[j] = make_ushort4(f2bf(v.x), f2bf(v.y), f2bf(v.z), f2bf(v.w));
  } else if (i < PREP_C) {
    int j = i - PREP_B;
    float4 v = pw[j];
    pwb[j] = make_ushort4(f2bf(v.x), f2bf(v.y), f2bf(v.z), f2bf(v.w));
  } else if (i < PREP_E) {
    int j = i - PREP_C;
    int n = j >> 5, f = j & 31;
    float inv = powf(10000.f, -(2.f * f) / 64.f);
    float s, c;
    sincosf((float)n * inv, &s, &c);
    tab[j] = make_float2(c, s);
  }
}

// ---------------- bf16 GEMM: C = A * Bt^T, 128x128 tile, BK=64 ----------------
// R16-proven loop (single-buffer LDS + __syncthreads; compiler-scheduled).
// 1-D grid with XCD-locality decode: xcd=bid&7 owns 4 row-panels (A stays hot in
// its L2); within XCD row-in-group fastest -> B panel reused 4x back-to-back.
// Epilogue: 4x4 in-quad register transpose -> wide stores:
//   EPI=0: float4 fp32 out + bias (proj)
//   EPI=1: bias + in-lane RoPE + uint2 scatter; q pre-scaled by SC2;
//     K tiled [bh][n/64][d/8][n&63][d&7]; V tiled [bh][n/64][(n&63)/8][d][n&7]
template <int EPI>
__global__ __launch_bounds__(256, 2) void k_gemm(
    const u16* __restrict__ A, const u16* __restrict__ Bt,
    const float* __restrict__ bias, int K,
    float* __restrict__ out_f, u16* __restrict__ qb, u16* __restrict__ kb,
    u16* __restrict__ vtb, const float2* __restrict__ tab) {
  __shared__ u16 As[128 * 64];
  __shared__ u16 Bs[128 * 64];
  const int tid = threadIdx.x;
  const int wid = tid >> 6, lane = tid & 63;
  const int lq = lane & 15, g = lane >> 4;
  const int wr = wid >> 1, wc = wid & 1;
  // XCD-locality decode: 4 row-panels per XCD, row-in-group fastest
  const int bid = blockIdx.x;
  const int xcd = bid & 7, idx = bid >> 3;
  const int brow = (xcd * 4 + (idx & 3)) * 128;
  const int bcol = (idx >> 2) * 128;
  f32x4 acc[4][4] = {};
  const u16* Ab = A + (size_t)brow * K;
  const u16* Bb = Bt + (size_t)bcol * K;

  for (int k0 = 0; k0 < K; k0 += 64) {
#pragma unroll
    for (int t = 0; t < 4; t++) {
      int rl = wid * 32 + t * 8 + (lane >> 3);
      int cs = (lane & 7) ^ (rl & 7);
      gload16(Ab + (size_t)rl * K + k0 + cs * 8, &As[(wid * 32 + t * 8) * 64]);
      gload16(Bb + (size_t)rl * K + k0 + cs * 8, &Bs[(wid * 32 + t * 8) * 64]);
    }
    __syncthreads();
#pragma unroll
    for (int kc = 0; kc < 2; kc++) {
      short8 af[4], bfr[4];
#pragma unroll
      for (int mt = 0; mt < 4; mt++) {
        int r = wr * 64 + mt * 16 + lq;
        af[mt] = *reinterpret_cast<const short8*>(&As[r * 64 + (((kc * 4 + g) ^ (r & 7)) * 8)]);
      }
#pragma unroll
      for (int nt = 0; nt < 4; nt++) {
        int r = wc * 64 + nt * 16 + lq;
        bfr[nt] = *reinterpret_cast<const short8*>(&Bs[r * 64 + (((kc * 4 + g) ^ (r & 7)) * 8)]);
      }
#pragma unroll
      for (int mt = 0; mt < 4; mt++)
#pragma unroll
        for (int nt = 0; nt < 4; nt++)
          acc[mt][nt] = __builtin_amdgcn_mfma_f32_16x16x32_bf16(af[mt], bfr[nt], acc[mt][nt], 0, 0, 0);
    }
    __syncthreads();
  }

#pragma unroll
  for (int mt = 0; mt < 4; mt++) {
    int row0 = brow + wr * 64 + mt * 16 + g * 4;
#pragma unroll
    for (int nt = 0; nt < 4; nt++) {
      int col = bcol + wc * 64 + nt * 16 + lq;
      float bv = bias[col];
      float v0 = acc[mt][nt][0] + bv;
      float v1 = acc[mt][nt][1] + bv;
      float v2 = acc[mt][nt][2] + bv;
      float v3 = acc[mt][nt][3] + bv;

      if (EPI == 1) {
        int which = col >> 10;
        if (which == 2) {
          // V tiled store: 4 consecutive n within one (kvchunk,d) run -> one 8B store
          int hd = col & 1023, d = hd & 63;
          int bb = row0 >> 11, n0 = row0 & 2047;
          int bh = bb * NH + (hd >> 6);
          uint2 pv = make_uint2(pk2(v0, v1), pk2(v2, v3));
          size_t idx2 = ((((size_t)bh * 32 + (n0 >> 6)) * 8 + ((n0 >> 3) & 7)) * 64 + d) * 8 + (n0 & 7);
          *reinterpret_cast<uint2*>(&vtb[idx2]) = pv;
          continue;
        }
      }

      // ---- 4x4 in-quad transpose: lane -> token row0+(lane&3), features f0..f0+3 ----
      { float u = (lane & 1) ? v0 : v1; float s = __shfl_xor(u, 1); if (lane & 1) v0 = s; else v1 = s; }
      { float u = (lane & 1) ? v2 : v3; float s = __shfl_xor(u, 1); if (lane & 1) v2 = s; else v3 = s; }
      { float u = (lane & 2) ? v0 : v2; float s = __shfl_xor(u, 2); if (lane & 2) v0 = s; else v2 = s; }
      { float u = (lane & 2) ? v1 : v3; float s = __shfl_xor(u, 2); if (lane & 2) v1 = s; else v3 = s; }
      const int rr = row0 + (lane & 3);          // token
      const int f0 = col & ~3;                   // feature base (4-aligned)

      if (EPI == 0) {
        *reinterpret_cast<float4*>(&out_f[(size_t)rr * DIM + f0]) = make_float4(v0, v1, v2, v3);
      } else {
        int which = f0 >> 10, hd = f0 & 1023, hdh = hd >> 6, d0 = hd & 63;
        int bb = rr >> 11, n = rr & 2047;
        int bh = bb * NH + hdh;
        // in-lane RoPE: (v0,v1) and (v2,v3) are even/odd pairs
        float2 cs0 = tab[n * 32 + (d0 >> 1)];
        float2 cs1 = tab[n * 32 + (d0 >> 1) + 1];
        float e0 = fmaf(-v1, cs0.y, v0 * cs0.x);
        float o0 = fmaf( v0, cs0.y, v1 * cs0.x);
        float e1 = fmaf(-v3, cs1.y, v2 * cs1.x);
        float o1 = fmaf( v2, cs1.y, v3 * cs1.x);
        if (which == 0) {
          uint2 pv = make_uint2(pk2(e0 * SC2, o0 * SC2), pk2(e1 * SC2, o1 * SC2));
          *reinterpret_cast<uint2*>(&qb[((size_t)bh * SEQ + n) * HDIM + d0]) = pv;
        } else {
          size_t idx2 = ((((size_t)bh * 32 + (n >> 6)) * 8 + (d0 >> 3)) * 64 + (n & 63)) * 8 + (d0 & 7);
          *reinterpret_cast<uint2*>(&kb[idx2]) = make_uint2(pk2(e0, o0), pk2(e1, o1));
        }
      }
    }
  }
}

// ---------------- flash attention: LDS-shared KV + cross-tile pipeline (R15/R18) ----------------
// grid 512 (XCD-swizzled: 4 heads/XCD), 256 thr = 4 waves x 32 q. KV staged ONCE per
// block via global_load_lds into 4 rotating 16KB buffers (blocked layout -> linear
// stage, conflict-free b128 reads). One barrier/tile, counted vmcnt(4).
// QK(t) on matrix pipe overlaps exp/pack(t-1) on VALU; PV(t-1) reads resident V.
// No-max softmax (Q pre-scaled), raw v_exp, cvt_pk+permlane pack, ones-MFMA denom.
__global__ __launch_bounds__(256) void k_attn(
    const u16* __restrict__ qg, const u16* __restrict__ kg,
    const u16* __restrict__ vg, u16* __restrict__ aout) {
  __shared__ __align__(16) char smem[65536];   // 4 buf x [K 8KB | V 8KB]
  const int tid = threadIdx.x;
  const int wid = tid >> 6, lane = tid & 63;
  const int l31 = lane & 31, h = lane >> 5;

  // XCD-aware decode: bid&7 = XCD; 4 consecutive heads per XCD
  const int bid = blockIdx.x;
  const int xcd = bid & 7, slot = bid >> 3;      // slot 0..63
  const int bh = xcd * 4 + (slot >> 4);
  const int qt = slot & 15;
  const int b = bh >> 4, hh = bh & 15;
  const int q0 = qt * 128 + wid * 32;            // this wave's 32 q-rows

  const u16* kbase = kg + (size_t)bh * SEQ * HDIM;   // 32 tiles x 4096 u16 (blocked)
  const u16* vbase = vg + (size_t)bh * SEQ * HDIM;

  // Q B-frags (pre-scaled by SC2): chunk c -> d = c*16 + h*8 + j
  const u16* qrow = qg + ((size_t)bh * SEQ + q0 + l31) * HDIM;
  short8 qf[4];
#pragma unroll
  for (int c = 0; c < 4; c++)
    qf[c] = *reinterpret_cast<const short8*>(qrow + c * 16 + h * 8);

  // all-ones bf16 A-frag for the denominator MFMA (layout-independent)
  short8 ones;
#pragma unroll
  for (int i = 0; i < 8; i++) ones[i] = (short)0x3F80;

  // chunk-major frag offsets: block (2c+h), row l31 (+512B for rows 32..63)
  int koff[4];
#pragma unroll
  for (int c = 0; c < 4; c++)
    koff[c] = (2 * c + h) * 1024 + l31 * 16;

  f32x16 sA0, sA1, sB0, sB1;
  f32x16 oA = {}, oB = {}, ls = {};

  // stage one 64-kv tile (K 8KB + V 8KB): wave stages chunk-blocks {wid, wid+4}
  auto stage = [&](int buf, int tidx) {          // 4 gloads/lane
    char* kd = smem + buf * 16384;
    const u16* kt = kbase + (size_t)tidx * 4096 + lane * 8;
    const u16* vt = vbase + (size_t)tidx * 4096 + lane * 8;
#pragma unroll
    for (int i = 0; i < 2; i++) {
      int g = wid + i * 4;
      gload16(kt + g * 512, kd + g * 1024);
      gload16(vt + g * 512, kd + 8192 + g * 1024);
    }
  };

  const int NT = SEQ / 64;                       // 32

  // one pipelined tile: wait buf(t); QK(t)->sn while exp/pack(S(t-1)=sc)+PV(t-1)
  auto body = [&](f32x16& sc0, f32x16& sc1, f32x16& sn0, f32x16& sn1, int t, bool last) {
    if (!last) asm volatile("s_waitcnt vmcnt(4)" ::: "memory");
    else       asm volatile("s_waitcnt vmcnt(0)" ::: "memory");
    __builtin_amdgcn_s_barrier();                // buf(t) staged for everyone

    const char* kbp = smem + (t & 3) * 16384;
    const char* vbp = smem + ((t - 1) & 3) * 16384 + 8192;

#pragma unroll
    for (int c = 0; c < 4; c++) {
      short8 kf0 = *reinterpret_cast<const short8*>(kbp + koff[c]);
      short8 kf1 = *reinterpret_cast<const short8*>(kbp + koff[c] + 512);
      __builtin_amdgcn_s_setprio(1);
      if (c == 0) {
        f32x16 z = {};
        sn0 = __builtin_amdgcn_mfma_f32_32x32x16_bf16(kf0, qf[0], z, 0, 0, 0);
        sn1 = __builtin_amdgcn_mfma_f32_32x32x16_bf16(kf1, qf[0], z, 0, 0, 0);
      } else {
        sn0 = __builtin_amdgcn_mfma_f32_32x32x16_bf16(kf0, qf[c], sn0, 0, 0, 0);
        sn1 = __builtin_amdgcn_mfma_f32_32x32x16_bf16(kf1, qf[c], sn1, 0, 0, 0);
      }
      __builtin_amdgcn_s_setprio(0);

      if (c == 0 && t + 2 < NT) stage((t + 2) & 3, t + 2);   // prefetch 2 ahead

      // V(t-1) frags (issued early: latency hides under exp VALU)
      short8 vf0 = *reinterpret_cast<const short8*>(vbp + koff[c]);
      short8 vf1 = *reinterpret_cast<const short8*>(vbp + koff[c] + 512);

      // exp + pack chunk c of S(t-1)
      f32x16& sv = (c < 2) ? sc0 : sc1;
      const int e0 = (c & 1) * 8;
      float e[8];
#pragma unroll
      for (int j = 0; j < 8; j++) e[j] = vexp2(sv[e0 + j]);
      u32 a0 = cvtpk(e[0], e[1]), a1 = cvtpk(e[2], e[3]);
      u32 b0 = cvtpk(e[4], e[5]), b1 = cvtpk(e[6], e[7]);
      auto r0 = __builtin_amdgcn_permlane32_swap(a0, b0, false, false);
      auto r1 = __builtin_amdgcn_permlane32_swap(a1, b1, false, false);
      union { u32 u[4]; short8 v; } pp;
      pp.u[0] = r0[0]; pp.u[1] = r1[0]; pp.u[2] = r0[1]; pp.u[3] = r1[1];
      short8 pf = pp.v;

      __builtin_amdgcn_s_setprio(1);
      oA = __builtin_amdgcn_mfma_f32_32x32x16_bf16(vf0,  pf, oA, 0, 0, 0);
      oB = __builtin_amdgcn_mfma_f32_32x32x16_bf16(vf1,  pf, oB, 0, 0, 0);
      ls = __builtin_amdgcn_mfma_f32_32x32x16_bf16(ones, pf, ls, 0, 0, 0);
      __builtin_amdgcn_s_setprio(0);
    }
  };

  // ---- prologue: stage 0,1; QK(0) only ----
  stage(0, 0);
  stage(1, 1);
  asm volatile("s_waitcnt vmcnt(4)" ::: "memory");
  __builtin_amdgcn_s_barrier();
  {
    const char* kbp = smem;                      // buf0 = tile 0
    f32x16 z = {};
    sA0 = z; sA1 = z;
#pragma unroll
    for (int c = 0; c < 4; c++) {
      short8 kf0 = *reinterpret_cast<const short8*>(kbp + koff[c]);
      short8 kf1 = *reinterpret_cast<const short8*>(kbp + koff[c] + 512);
      __builtin_amdgcn_s_setprio(1);
      sA0 = __builtin_amdgcn_mfma_f32_32x32x16_bf16(kf0, qf[c], sA0, 0, 0, 0);
      sA1 = __builtin_amdgcn_mfma_f32_32x32x16_bf16(kf1, qf[c], sA1, 0, 0, 0);
      __builtin_amdgcn_s_setprio(0);
      if (c == 0) stage(2, 2);
    }
  }

  // ---- main: t = 1..30 in pairs, then t = 31 ----
#pragma unroll 1
  for (int i = 0; i < 15; i++) {
    body(sA0, sA1, sB0, sB1, 2 * i + 1, false);  // QK(2i+1)->sB, consume S(2i)=sA
    body(sB0, sB1, sA0, sA1, 2 * i + 2, false);  // QK(2i+2)->sA, consume S(2i+1)=sB
  }
  body(sA0, sA1, sB0, sB1, 31, true);            // QK(31)->sB, consume S(30)=sA

  // ---- epilogue: consume S(31)=sB with V(31) in buf3 (still resident) ----
  {
    const char* vbp = smem + 3 * 16384 + 8192;
#pragma unroll
    for (int c = 0; c < 4; c++) {
      short8 vf0 = *reinterpret_cast<const short8*>(vbp + koff[c]);
      short8 vf1 = *reinterpret_cast<const short8*>(vbp + koff[c] + 512);
      f32x16& sv = (c < 2) ? sB0 : sB1;
      const int e0 = (c & 1) * 8;
      float e[8];
#pragma unroll
      for (int j = 0; j < 8; j++) e[j] = vexp2(sv[e0 + j]);
      u32 a0 = cvtpk(e[0], e[1]), a1 = cvtpk(e[2], e[3]);
      u32 b0 = cvtpk(e[4], e[5]), b1 = cvtpk(e[6], e[7]);
      auto r0 = __builtin_amdgcn_permlane32_swap(a0, b0, false, false);
      auto r1 = __builtin_amdgcn_permlane32_swap(a1, b1, false, false);
      union { u32 u[4]; short8 v; } pp;
      pp.u[0] = r0[0]; pp.u[1] = r1[0]; pp.u[2] = r0[1]; pp.u[3] = r1[1];
      short8 pf = pp.v;
      oA = __builtin_amdgcn_mfma_f32_32x32x16_bf16(vf0,  pf, oA, 0, 0, 0);
      oB = __builtin_amdgcn_mfma_f32_32x32x16_bf16(vf1,  pf, oB, 0, 0, 0);
      ls = __builtin_amdgcn_mfma_f32_32x32x16_bf16(ones, pf, ls, 0, 0, 0);
    }
  }

  // ls[r] identical for all r: full-sequence row sum for q = l31 (both lane halves)
  float invl = 1.0f / ls[0];
  int n = q0 + l31;
  u16* op = aout + ((size_t)(b * SEQ + n)) * DIM + hh * HDIM;
#pragma unroll
  for (int g = 0; g < 4; g++) {
    u32 w0 = pk2(oA[4 * g] * invl, oA[4 * g + 1] * invl);
    u32 w1 = pk2(oA[4 * g + 2] * invl, oA[4 * g + 3] * invl);
    *reinterpret_cast<uint2*>(op + 8 * g + 4 * h) = make_uint2(w0, w1);
    u32 x0 = pk2(oB[4 * g] * invl, oB[4 * g + 1] * invl);
    u32 x1 = pk2(oB[4 * g + 2] * invl, oB[4 * g + 3] * invl);
    *reinterpret_cast<uint2*>(op + 32 + 8 * g + 4 * h) = make_uint2(x0, x1);
  }
}

// ---------------- launch ----------------
extern "C" void kernel_launch(void* const* d_in, const int* in_sizes, int n_in,
                              void* d_out, int out_size, void* d_ws, size_t ws_size,
                              hipStream_t stream) {
  (void)in_sizes; (void)n_in; (void)out_size; (void)ws_size;
  const float* x      = (const float*)d_in[0];
  const float* qkv_w  = (const float*)d_in[1];
  const float* qkv_b  = (const float*)d_in[2];
  const float* proj_w = (const float*)d_in[3];
  const float* proj_b = (const float*)d_in[4];
  float* out = (float*)d_out;

  char* w = (char*)d_ws;
  u16* xb     = (u16*)w;  w += (size_t)MTOK * DIM * 2;
  u16* wqkvb  = (u16*)w;  w += (size_t)3 * DIM * DIM * 2;
  u16* wprojb = (u16*)w;  w += (size_t)DIM * DIM * 2;
  u16* qb     = (u16*)w;  w += (size_t)BHN * SEQ * HDIM * 2;
  u16* kb     = (u16*)w;  w += (size_t)BHN * SEQ * HDIM * 2;
  u16* vtb    = (u16*)w;  w += (size_t)BHN * SEQ * HDIM * 2;
  u16* aout   = (u16*)w;  w += (size_t)MTOK * DIM * 2;
  float2* tab = (float2*)w;

  k_prep<<<(PREP_E + 255) / 256, 256, 0, stream>>>(
      (const float4*)x, (const float4*)qkv_w, (const float4*)proj_w,
      (ushort4*)xb, (ushort4*)wqkvb, (ushort4*)wprojb, tab);

  // grid: 24 cols x 32 rows = 768 blocks, XCD-locality decode inside
  k_gemm<1><<<768, 256, 0, stream>>>(
      xb, wqkvb, qkv_b, DIM, nullptr, qb, kb, vtb, tab);

  k_attn<<<512, 256, 0, stream>>>(qb, kb, vtb, aout);

  // grid: 8 cols x 32 rows = 256 blocks
  k_gemm<0><<<256, 256, 0, stream>>>(
      aout, wprojb, proj_b, DIM, out, nullptr, nullptr, nullptr, nullptr);
}